// Round 3
// baseline (597.741 us; speedup 1.0000x reference)
//
#include <hip/hip_runtime.h>

// HiPPO-LegS scan, fp32 chunked associative scan — round 3.
// Structure change vs round 2: A/M operands streamed from GLOBAL into registers
// (broadcast float4 along k, 1-deep prefetch) — no LDS staging of matrices, one
// barrier per product/apply. Downsweep fused into one kernel (ds_all).
// All matrices lower-triangular -> quad-granular k-window skips (rows & cols).
// Kernels: k1 (chunk summaries) -> 5x k2 (pair combines) -> ds_all (E1 entries)
// -> k3 (replay + output). Workspace: 504 units + E1 = 43.4 MB.

#define NN 128
#define NB 32
#define LDP 164    // P row stride: 128 M cols + 32 w cols + pad (mod32=4)
#define LDS_S 36   // state tile stride (128 x 36)
#define UNIT 20480 // floats per unit: 128*128 M + 128*32 w
#define WOFF 16384

__device__ __forceinline__ float comp4(const float4& v, int kk) {
  return ((const float*)&v)[kk];
}

// ---------------------------------------------------------------------------
// prod256: out = Ag * P (augmented: M cols 0..127, w cols 128..159), Ag streamed
// from global. 256 threads: g=tid>>4 owns row quads {4g..4g+3, 124-4g..127-4g};
// tj=tid&15 owns cols {4tj, 64+4tj, 128+2tj}. Tri-skips: rows k<=row (k4<=g /
// k4<=31-g), M-cols k>=col (k4>=tj / k4>=16+tj) — exact at quad granularity.
// MODE 0: writeback into P (2 barriers). MODE 1: store to global unit + addW.
// MODE 2: store to global unit + bv⊗x (u-add fused).
template <int MODE>
__device__ __forceinline__ void prod256(const float* __restrict__ Ag,
                                        float* __restrict__ P,
                                        float* __restrict__ oM, float* __restrict__ oW,
                                        const float* __restrict__ addW,
                                        const float* __restrict__ bv,
                                        const float* __restrict__ xr) {
  const int tid = threadIdx.x;
  const int g = tid >> 4, tj = tid & 15;
  const int rlo = 4 * g, rhi = 124 - 4 * g;
  const int cA = 4 * tj, cB = 64 + 4 * tj, cS = 128 + 2 * tj;
  const int k4hi = 31 - g;
  float accLA[4][4] = {}, accHA[4][4] = {}, accHB[4][4] = {};
  float accLS[4][2] = {}, accHS[4][2] = {};
  float4 aLo[4], aHi[4];
#pragma unroll
  for (int r = 0; r < 4; ++r) {
    aHi[r] = *(const float4*)(Ag + (rhi + r) * NN);
    aLo[r] = *(const float4*)(Ag + (rlo + r) * NN);
  }
  for (int k4 = 0; k4 <= k4hi; ++k4) {
    const bool dlo = (k4 <= g);
    const bool pa = (k4 >= tj);
    const bool pb = (k4 >= 16 + tj);
    const int kn = k4 + 1;
    const bool pfh = (kn <= k4hi), pfl = (kn <= g);
    float4 nLo[4], nHi[4];
#pragma unroll
    for (int r = 0; r < 4; ++r) {
      nHi[r] = pfh ? *(const float4*)(Ag + (rhi + r) * NN + kn * 4) : make_float4(0.f, 0.f, 0.f, 0.f);
      nLo[r] = pfl ? *(const float4*)(Ag + (rlo + r) * NN + kn * 4) : make_float4(0.f, 0.f, 0.f, 0.f);
    }
#pragma unroll
    for (int kk = 0; kk < 4; ++kk) {
      const int k = k4 * 4 + kk;
      const float2 pw = *(const float2*)(P + k * LDP + cS);
      float ah[4], al[4];
#pragma unroll
      for (int r = 0; r < 4; ++r) { ah[r] = comp4(aHi[r], kk); al[r] = comp4(aLo[r], kk); }
#pragma unroll
      for (int r = 0; r < 4; ++r) { accHS[r][0] += ah[r] * pw.x; accHS[r][1] += ah[r] * pw.y; }
      if (dlo) {
#pragma unroll
        for (int r = 0; r < 4; ++r) { accLS[r][0] += al[r] * pw.x; accLS[r][1] += al[r] * pw.y; }
      }
      if (pa) {
        const float4 pA = *(const float4*)(P + k * LDP + cA);
#pragma unroll
        for (int r = 0; r < 4; ++r) {
          accHA[r][0] += ah[r] * pA.x; accHA[r][1] += ah[r] * pA.y;
          accHA[r][2] += ah[r] * pA.z; accHA[r][3] += ah[r] * pA.w;
        }
        if (dlo) {
#pragma unroll
          for (int r = 0; r < 4; ++r) {
            accLA[r][0] += al[r] * pA.x; accLA[r][1] += al[r] * pA.y;
            accLA[r][2] += al[r] * pA.z; accLA[r][3] += al[r] * pA.w;
          }
        }
      }
      if (pb) {
        const float4 pB = *(const float4*)(P + k * LDP + cB);
#pragma unroll
        for (int r = 0; r < 4; ++r) {
          accHB[r][0] += ah[r] * pB.x; accHB[r][1] += ah[r] * pB.y;
          accHB[r][2] += ah[r] * pB.z; accHB[r][3] += ah[r] * pB.w;
        }
      }
    }
#pragma unroll
    for (int r = 0; r < 4; ++r) { aHi[r] = nHi[r]; aLo[r] = nLo[r]; }
  }
  if (MODE == 0) {
    __syncthreads();  // all P reads done before overwrite
#pragma unroll
    for (int r = 0; r < 4; ++r) {
      *(float4*)(P + (rlo + r) * LDP + cA) =
          make_float4(accLA[r][0], accLA[r][1], accLA[r][2], accLA[r][3]);
      *(float4*)(P + (rlo + r) * LDP + cB) = make_float4(0.f, 0.f, 0.f, 0.f);
      *(float2*)(P + (rlo + r) * LDP + cS) = make_float2(accLS[r][0], accLS[r][1]);
      *(float4*)(P + (rhi + r) * LDP + cA) =
          make_float4(accHA[r][0], accHA[r][1], accHA[r][2], accHA[r][3]);
      *(float4*)(P + (rhi + r) * LDP + cB) =
          make_float4(accHB[r][0], accHB[r][1], accHB[r][2], accHB[r][3]);
      *(float2*)(P + (rhi + r) * LDP + cS) = make_float2(accHS[r][0], accHS[r][1]);
    }
    __syncthreads();
  } else {
    float2 xx = make_float2(0.f, 0.f);
    if (MODE == 2) xx = *(const float2*)(xr + 2 * tj);
#pragma unroll
    for (int r = 0; r < 4; ++r) {
      *(float4*)(oM + (rlo + r) * NN + cA) =
          make_float4(accLA[r][0], accLA[r][1], accLA[r][2], accLA[r][3]);
      *(float4*)(oM + (rlo + r) * NN + cB) = make_float4(0.f, 0.f, 0.f, 0.f);
      *(float4*)(oM + (rhi + r) * NN + cA) =
          make_float4(accHA[r][0], accHA[r][1], accHA[r][2], accHA[r][3]);
      *(float4*)(oM + (rhi + r) * NN + cB) =
          make_float4(accHB[r][0], accHB[r][1], accHB[r][2], accHB[r][3]);
      float wl0 = accLS[r][0], wl1 = accLS[r][1];
      float wh0 = accHS[r][0], wh1 = accHS[r][1];
      if (MODE == 1) {
        wl0 += addW[(rlo + r) * NB + 2 * tj]; wl1 += addW[(rlo + r) * NB + 2 * tj + 1];
        wh0 += addW[(rhi + r) * NB + 2 * tj]; wh1 += addW[(rhi + r) * NB + 2 * tj + 1];
      } else if (MODE == 2) {
        const float bl = bv[rlo + r], bh = bv[rhi + r];
        wl0 += bl * xx.x; wl1 += bl * xx.y;
        wh0 += bh * xx.x; wh1 += bh * xx.y;
      }
      *(float2*)(oW + (rlo + r) * NB + 2 * tj) = make_float2(wl0, wl1);
      *(float2*)(oW + (rhi + r) * NB + 2 * tj) = make_float2(wh0, wh1);
    }
  }
}

// ---------------------------------------------------------------------------
// apply256: Sout[r][b] = sum_k Mg[r][k]*Sin[k][b] (+w or +bv⊗x). Mg streamed
// from global. 256 threads: rq=tid>>4 owns row quads {4rq.., 124-4rq..};
// bp=tid&15 owns batch pair 2bp. Exactly one __syncthreads (at end).
template <int WM>  // 1: +global w, 2: +bv⊗x
__device__ __forceinline__ void apply256(const float* __restrict__ Mg,
                                         const float* __restrict__ wg,
                                         const float* __restrict__ bv,
                                         const float* __restrict__ xr,
                                         const float* __restrict__ Sin,
                                         float* __restrict__ Sout) {
  const int tid = threadIdx.x;
  const int rq = tid >> 4, bp = tid & 15;
  const int b0 = 2 * bp;
  const int rlo = 4 * rq, rhi = 124 - 4 * rq;
  const int k4hi = 31 - rq;
  float accL[4][2] = {}, accH[4][2] = {};
  float4 aLo[4], aHi[4];
#pragma unroll
  for (int r = 0; r < 4; ++r) {
    aHi[r] = *(const float4*)(Mg + (rhi + r) * NN);
    aLo[r] = *(const float4*)(Mg + (rlo + r) * NN);
  }
  for (int k4 = 0; k4 <= k4hi; ++k4) {
    const bool dlo = (k4 <= rq);
    const int kn = k4 + 1;
    const bool pfh = (kn <= k4hi), pfl = (kn <= rq);
    float4 nLo[4], nHi[4];
#pragma unroll
    for (int r = 0; r < 4; ++r) {
      nHi[r] = pfh ? *(const float4*)(Mg + (rhi + r) * NN + kn * 4) : make_float4(0.f, 0.f, 0.f, 0.f);
      nLo[r] = pfl ? *(const float4*)(Mg + (rlo + r) * NN + kn * 4) : make_float4(0.f, 0.f, 0.f, 0.f);
    }
#pragma unroll
    for (int kk = 0; kk < 4; ++kk) {
      const int k = k4 * 4 + kk;
      const float2 s = *(const float2*)(Sin + k * LDS_S + b0);
#pragma unroll
      for (int r = 0; r < 4; ++r) {
        const float ah = comp4(aHi[r], kk);
        accH[r][0] += ah * s.x; accH[r][1] += ah * s.y;
      }
      if (dlo) {
#pragma unroll
        for (int r = 0; r < 4; ++r) {
          const float al = comp4(aLo[r], kk);
          accL[r][0] += al * s.x; accL[r][1] += al * s.y;
        }
      }
    }
#pragma unroll
    for (int r = 0; r < 4; ++r) { aHi[r] = nHi[r]; aLo[r] = nLo[r]; }
  }
  float2 xx = make_float2(0.f, 0.f);
  if (WM == 2) xx = *(const float2*)(xr + b0);
#pragma unroll
  for (int r = 0; r < 4; ++r) {
    float l0 = accL[r][0], l1 = accL[r][1], h0 = accH[r][0], h1 = accH[r][1];
    if (WM == 1) {
      l0 += wg[(rlo + r) * NB + b0]; l1 += wg[(rlo + r) * NB + b0 + 1];
      h0 += wg[(rhi + r) * NB + b0]; h1 += wg[(rhi + r) * NB + b0 + 1];
    } else if (WM == 2) {
      const float bl = bv[rlo + r], bh = bv[rhi + r];
      l0 += bl * xx.x; l1 += bl * xx.y;
      h0 += bh * xx.x; h1 += bh * xx.y;
    }
    *(float2*)(Sout + (rlo + r) * LDS_S + b0) = make_float2(l0, l1);
    *(float2*)(Sout + (rhi + r) * LDS_S + b0) = make_float2(h0, h1);
  }
  __syncthreads();
}

// ---------------------------------------------------------------------------
// K1: chunk summaries (M_c, w_c), chunk = 4 timesteps. 256 blocks x 256 thr.
__global__ __launch_bounds__(256) void k1_chunks(const float* __restrict__ A,
                                                 const float* __restrict__ x,
                                                 const float* __restrict__ Bv,
                                                 float* __restrict__ U) {
  __shared__ float P[128 * LDP];
  const int tid = threadIdx.x;
  const int c = blockIdx.x;
  const int l0 = 4 * c;
  const float* A0 = A + (size_t)l0 * NN * NN;
#pragma unroll
  for (int q = 0; q < 16; ++q) {
    const int f = tid + 256 * q;
    const int i = f >> 5, j4 = (f & 31) * 4;
    *(float4*)(P + i * LDP + j4) = *(const float4*)(A0 + i * NN + j4);
  }
  {
    const float* xl = x + (size_t)l0 * NB;
    const float* bvl = Bv + (size_t)l0 * NN;
#pragma unroll
    for (int q = 0; q < 4; ++q) {
      const int e = tid + 256 * q;
      const int r = e >> 3, b4 = (e & 7) * 4;
      const float4 xv = *(const float4*)(xl + b4);
      const float br = bvl[r];
      *(float4*)(P + r * LDP + NN + b4) = make_float4(br * xv.x, br * xv.y, br * xv.z, br * xv.w);
    }
  }
  __syncthreads();
  for (int j = 1; j <= 2; ++j) {
    const int l = l0 + j;
    prod256<0>(A + (size_t)l * NN * NN, P, nullptr, nullptr, nullptr, nullptr, nullptr);
    const float* xl = x + (size_t)l * NB;
    const float* bvl = Bv + (size_t)l * NN;
#pragma unroll
    for (int q = 0; q < 4; ++q) {
      const int e = tid + 256 * q;
      const int r = e >> 3, b4 = (e & 7) * 4;
      const float4 xv = *(const float4*)(xl + b4);
      const float br = bvl[r];
      float* p = P + r * LDP + NN + b4;
      p[0] += br * xv.x; p[1] += br * xv.y; p[2] += br * xv.z; p[3] += br * xv.w;
    }
    __syncthreads();
  }
  float* o = U + (size_t)c * UNIT;
  prod256<2>(A + (size_t)(l0 + 3) * NN * NN, P, o, o + WOFF, nullptr,
             Bv + (size_t)(l0 + 3) * NN, x + (size_t)(l0 + 3) * NB);
}

// ---------------------------------------------------------------------------
// K2: pair combine, out[n] = hi o lo. One block per node, 256 thr.
__global__ __launch_bounds__(256) void k2_combine(const float* __restrict__ Uc,
                                                  float* __restrict__ Uo) {
  __shared__ float P[128 * LDP];
  const int tid = threadIdx.x;
  const int n = blockIdx.x;
  const float* lo = Uc + (size_t)(2 * n) * UNIT;
  const float* hi = Uc + (size_t)(2 * n + 1) * UNIT;
  float* o = Uo + (size_t)n * UNIT;
#pragma unroll
  for (int q = 0; q < 16; ++q) {
    const int f = tid + 256 * q;
    const int i = f >> 5, j4 = (f & 31) * 4;
    *(float4*)(P + i * LDP + j4) = *(const float4*)(lo + i * NN + j4);
  }
#pragma unroll
  for (int q = 0; q < 4; ++q) {
    const int e = tid + 256 * q;
    const int r = e >> 3, b4 = (e & 7) * 4;
    *(float4*)(P + r * LDP + NN + b4) = *(const float4*)(lo + WOFF + r * NB + b4);
  }
  __syncthreads();
  prod256<1>(hi, P, o, o + WOFF, hi + WOFF, nullptr, nullptr);
}

// ---------------------------------------------------------------------------
// ds_all: E1[n] (entry state of chunk-pair n) for n in [0,128): scan level-5
// group summaries (<=7 applies) then binary walk L4->L1 (<=4 applies).
__global__ __launch_bounds__(256) void ds_all(const float* __restrict__ U,
                                              float* __restrict__ E1) {
  __shared__ float Sa[128 * LDS_S], Sb[128 * LDS_S];
  const int tid = threadIdx.x;
  const int n = blockIdx.x;
#pragma unroll
  for (int q = 0; q < 4; ++q) {
    const int e = tid + 256 * q;
    const int r = e >> 3, b4 = (e & 7) * 4;
    *(float4*)(Sa + r * LDS_S + b4) = make_float4(0.f, 0.f, 0.f, 0.f);
  }
  __syncthreads();
  float* cur = Sa; float* nxt = Sb;
  const int g5 = n >> 4;
  for (int h = 0; h < g5; ++h) {
    const float* u = U + (size_t)(496 + h) * UNIT;
    apply256<1>(u, u + WOFF, nullptr, nullptr, cur, nxt);
    float* t = cur; cur = nxt; nxt = t;
  }
  if ((n >> 3) & 1) {
    const float* u = U + (size_t)(480 + (n >> 3) - 1) * UNIT;
    apply256<1>(u, u + WOFF, nullptr, nullptr, cur, nxt);
    float* t = cur; cur = nxt; nxt = t;
  }
  if ((n >> 2) & 1) {
    const float* u = U + (size_t)(448 + (n >> 2) - 1) * UNIT;
    apply256<1>(u, u + WOFF, nullptr, nullptr, cur, nxt);
    float* t = cur; cur = nxt; nxt = t;
  }
  if ((n >> 1) & 1) {
    const float* u = U + (size_t)(384 + (n >> 1) - 1) * UNIT;
    apply256<1>(u, u + WOFF, nullptr, nullptr, cur, nxt);
    float* t = cur; cur = nxt; nxt = t;
  }
  if (n & 1) {
    const float* u = U + (size_t)(256 + n - 1) * UNIT;
    apply256<1>(u, u + WOFF, nullptr, nullptr, cur, nxt);
    float* t = cur; cur = nxt; nxt = t;
  }
#pragma unroll
  for (int q = 0; q < 4; ++q) {
    const int e = tid + 256 * q;
    const int r = e >> 3, b4 = (e & 7) * 4;
    *(float4*)(E1 + (size_t)n * 4096 + r * NB + b4) = *(const float4*)(cur + r * LDS_S + b4);
  }
}

// ---------------------------------------------------------------------------
// K3: replay. Entry = E1[c/2] (+ L0 unit c-1 if odd), then 4 timesteps w/ output.
__global__ __launch_bounds__(256) void k3_replay(const float* __restrict__ A,
                                                 const float* __restrict__ x,
                                                 const float* __restrict__ Bv,
                                                 const float* __restrict__ U,
                                                 const float* __restrict__ E1,
                                                 float* __restrict__ out) {
  __shared__ float Sa[128 * LDS_S], Sb[128 * LDS_S];
  const int tid = threadIdx.x;
  const int c = blockIdx.x;
  const float* e1 = E1 + (size_t)(c >> 1) * 4096;
#pragma unroll
  for (int q = 0; q < 4; ++q) {
    const int e = tid + 256 * q;
    const int r = e >> 3, b4 = (e & 7) * 4;
    *(float4*)(Sa + r * LDS_S + b4) = *(const float4*)(e1 + r * NB + b4);
  }
  __syncthreads();
  float* cur = Sa; float* nxt = Sb;
  if (c & 1) {
    const float* u = U + (size_t)(c - 1) * UNIT;
    apply256<1>(u, u + WOFF, nullptr, nullptr, cur, nxt);
    float* t = cur; cur = nxt; nxt = t;
  }
  for (int j = 0; j < 4; ++j) {
    const int l = 4 * c + j;
    apply256<2>(A + (size_t)l * NN * NN, nullptr, Bv + (size_t)l * NN, x + (size_t)l * NB, cur, nxt);
    { float* t = cur; cur = nxt; nxt = t; }
#pragma unroll
    for (int q = 0; q < 4; ++q) {
      const int e = tid + 256 * q;
      const int b = e >> 5, n4 = (e & 31) * 4;
      const float4 v = make_float4(cur[(n4 + 0) * LDS_S + b], cur[(n4 + 1) * LDS_S + b],
                                   cur[(n4 + 2) * LDS_S + b], cur[(n4 + 3) * LDS_S + b]);
      *(float4*)(out + (size_t)l * 4096 + b * NN + n4) = v;
    }
    // next apply's trailing barrier orders these reads vs future buffer reuse
  }
}

// ---------------------------------------------------------------------------
extern "C" void kernel_launch(void* const* d_in, const int* in_sizes, int n_in,
                              void* d_out, int out_size, void* d_ws, size_t ws_size,
                              hipStream_t stream) {
  const float* x  = (const float*)d_in[0];  // (1024, 32)
  const float* A  = (const float*)d_in[1];  // (1024, 128, 128) lower-triangular
  const float* Bv = (const float*)d_in[2];  // (1024, 128)
  float* out = (float*)d_out;               // (1024, 32, 128)
  float* U = (float*)d_ws;                  // 504 units (41.3 MB) + E1 (2 MB)
  float* E1 = U + 504ull * UNIT;

  k1_chunks<<<256, 256, 0, stream>>>(A, x, Bv, U);
  // up-tree: L0(0..255) -> L1(256) -> L2(384) -> L3(448) -> L4(480) -> L5(496)
  k2_combine<<<128, 256, 0, stream>>>(U,                 U + 256ull * UNIT);
  k2_combine<<< 64, 256, 0, stream>>>(U + 256ull * UNIT, U + 384ull * UNIT);
  k2_combine<<< 32, 256, 0, stream>>>(U + 384ull * UNIT, U + 448ull * UNIT);
  k2_combine<<< 16, 256, 0, stream>>>(U + 448ull * UNIT, U + 480ull * UNIT);
  k2_combine<<<  8, 256, 0, stream>>>(U + 480ull * UNIT, U + 496ull * UNIT);
  ds_all<<<128, 256, 0, stream>>>(U, E1);
  k3_replay<<<256, 256, 0, stream>>>(A, x, Bv, U, E1, out);
}